// Round 13
// baseline (673.477 us; speedup 1.0000x reference)
//
#include <hip/hip_runtime.h>
#include <hip/hip_fp16.h>

#define N_NODES  100000
#define N_EDGES  1600000
#define NODE_DIM 64
#define HID      32
#define NUM_LAYERS 3
#define SCAN_B   1024   // elements per scan1 block

// 8-lane encoder decomposition
#define NPB4  32
#define GRID4 (N_NODES / NPB4)   // 3125, exact

// dist quantization: 15-bit fixed point, scale 2048 (dist < 16 w.p. ~1)
#define DIST_SCALE 2048.0f
#define DIST_INV   (1.0f / 2048.0f)

// ---------------------------------------------------------------------------
template <int IN>
__device__ __forceinline__ void mlp2(const float (&in)[IN],
                                     const float* __restrict__ w1,
                                     const float* __restrict__ b1,
                                     const float* __restrict__ w2,
                                     const float* __restrict__ b2,
                                     float (&out)[HID]) {
    float h[HID];
#pragma unroll
    for (int j = 0; j < HID; ++j) h[j] = b1[j];
    for (int k = 0; k < IN; ++k) {
        float v = in[k];
#pragma unroll
        for (int j = 0; j < HID; ++j) h[j] = fmaf(v, w1[k * HID + j], h[j]);
    }
#pragma unroll
    for (int j = 0; j < HID; ++j) h[j] = fmaxf(h[j], 0.0f);
#pragma unroll
    for (int j = 0; j < HID; ++j) out[j] = b2[j];
    for (int k = 0; k < HID; ++k) {
        float v = h[k];
#pragma unroll
        for (int j = 0; j < HID; ++j) out[j] = fmaf(v, w2[k * HID + j], out[j]);
    }
}

__device__ __forceinline__ void load_row32(const float* __restrict__ p, float* dst) {
    const float4* p4 = reinterpret_cast<const float4*>(p);
#pragma unroll
    for (int k = 0; k < HID / 4; ++k) {
        float4 v = p4[k];
        dst[4 * k + 0] = v.x; dst[4 * k + 1] = v.y;
        dst[4 * k + 2] = v.z; dst[4 * k + 3] = v.w;
    }
}

__device__ __forceinline__ void store_row32(float* __restrict__ p, const float* src) {
    float4* p4 = reinterpret_cast<float4*>(p);
#pragma unroll
    for (int k = 0; k < HID / 4; ++k) {
        float4 v;
        v.x = src[4 * k + 0]; v.y = src[4 * k + 1];
        v.z = src[4 * k + 2]; v.w = src[4 * k + 3];
        p4[k] = v;
    }
}

__device__ __forceinline__ void store_qrow_h(__half* __restrict__ qrow, const float* y) {
    uint4* p = reinterpret_cast<uint4*>(qrow);
#pragma unroll
    for (int i = 0; i < 4; ++i) {
        uint4 w;
#pragma unroll
        for (int j = 0; j < 4; ++j) {
            __half2 hh = __floats2half2_rn(y[i * 8 + j * 2], y[i * 8 + j * 2 + 1]);
            (&w.x)[j] = *reinterpret_cast<unsigned*>(&hh);
        }
        p[i] = w;
    }
}

// ------------------------------- sort: CSR by dst ---------------------------
__global__ void zero_int_kernel(int* __restrict__ p, int n) {
    int i = blockIdx.x * blockDim.x + threadIdx.x;
    if (i < n) p[i] = 0;
}

// count: 4 edges/thread, histogram of dst
__global__ void count_kernel(const int* __restrict__ ei, int* __restrict__ cnt) {
    int e0 = (blockIdx.x * blockDim.x + threadIdx.x) * 4;
    if (e0 >= N_EDGES) return;   // N_EDGES % 4 == 0
    int4 dd = *reinterpret_cast<const int4*>(ei + N_EDGES + e0);
    atomicAdd(&cnt[dd.x], 1);
    atomicAdd(&cnt[dd.y], 1);
    atomicAdd(&cnt[dd.z], 1);
    atomicAdd(&cnt[dd.w], 1);
}

// scan1: per-block exclusive scan of cnt (1024 elems/block of 256 threads)
__global__ void scan1_kernel(const int* __restrict__ cnt, int* __restrict__ off,
                             int* __restrict__ bsum) {
    __shared__ int lds[256];
    int tid = threadIdx.x;
    int base = blockIdx.x * SCAN_B + tid * 4;
    int v0 = (base + 0 < N_NODES) ? cnt[base + 0] : 0;
    int v1 = (base + 1 < N_NODES) ? cnt[base + 1] : 0;
    int v2 = (base + 2 < N_NODES) ? cnt[base + 2] : 0;
    int v3 = (base + 3 < N_NODES) ? cnt[base + 3] : 0;
    int s1 = v0, s2 = v0 + v1, s3 = v0 + v1 + v2;
    int tsum = s3 + v3;
    lds[tid] = tsum;
    __syncthreads();
    for (int d = 1; d < 256; d <<= 1) {
        int t = lds[tid];
        int u = (tid >= d) ? lds[tid - d] : 0;
        __syncthreads();
        lds[tid] = t + u;
        __syncthreads();
    }
    int excl = lds[tid] - tsum;
    if (base + 0 < N_NODES) off[base + 0] = excl;
    if (base + 1 < N_NODES) off[base + 1] = excl + s1;
    if (base + 2 < N_NODES) off[base + 2] = excl + s2;
    if (base + 3 < N_NODES) off[base + 3] = excl + s3;
    if (tid == 255) bsum[blockIdx.x] = lds[255];
}

__global__ void scan2_kernel(const int* __restrict__ bsum, int* __restrict__ boff, int nb) {
    __shared__ int lds[256];
    int tid = threadIdx.x;
    int v = (tid < nb) ? bsum[tid] : 0;
    lds[tid] = v;
    __syncthreads();
    for (int d = 1; d < 256; d <<= 1) {
        int t = lds[tid];
        int u = (tid >= d) ? lds[tid - d] : 0;
        __syncthreads();
        lds[tid] = t + u;
        __syncthreads();
    }
    if (tid < nb) boff[tid] = lds[tid] - v;
}

// scan3: finalize off and write the mutable copy used by the atomic scatter
__global__ void scan3_kernel(int* __restrict__ off, int* __restrict__ posm,
                             const int* __restrict__ boff) {
    int i = blockIdx.x * blockDim.x + threadIdx.x;
    if (i < N_NODES) {
        int v = off[i] + boff[i / SCAN_B];
        off[i] = v;
        posm[i] = v;
    }
}

// scatter with fused rank (atomic slot claim; order within a segment is
// irrelevant for a sum). 8 edges/thread = 8 independent atomic+store chains
// per lane (edge-phase law: ~12.5ns/edge/CU latency-bound; depth is the lever).
__global__ void scatter_kernel(const int* __restrict__ ei,
                               const float* __restrict__ pos,
                               int* __restrict__ posm,
                               unsigned* __restrict__ recs) {
    int e0 = (blockIdx.x * blockDim.x + threadIdx.x) * 8;
    if (e0 >= N_EDGES) return;   // N_EDGES % 8 == 0
    int4 sa = *reinterpret_cast<const int4*>(ei + e0);
    int4 sb = *reinterpret_cast<const int4*>(ei + e0 + 4);
    int4 da = *reinterpret_cast<const int4*>(ei + N_EDGES + e0);
    int4 db = *reinterpret_cast<const int4*>(ei + N_EDGES + e0 + 4);
    int sA[8] = {sa.x, sa.y, sa.z, sa.w, sb.x, sb.y, sb.z, sb.w};
    int dA[8] = {da.x, da.y, da.z, da.w, db.x, db.y, db.z, db.w};
#pragma unroll
    for (int k = 0; k < 8; ++k) {
        int s = sA[k], d = dA[k];
        float dx = pos[d * 3 + 0] - pos[s * 3 + 0];
        float dy = pos[d * 3 + 1] - pos[s * 3 + 1];
        float dz = pos[d * 3 + 2] - pos[s * 3 + 2];
        float dist = sqrtf(dx * dx + dy * dy + dz * dz);
        int dq = (int)(dist * DIST_SCALE);
        if (dq > 32767) dq = 32767;
        int t = atomicAdd(&posm[d], 1);
        recs[t] = ((unsigned)s << 15) | (unsigned)dq;
    }
}

// ------------------------------- model helpers (8-lane) ---------------------
__device__ __forceinline__ void fma4(float4& acc, float a, const float4 w) {
    acc.x = fmaf(a, w.x, acc.x);
    acc.y = fmaf(a, w.y, acc.y);
    acc.z = fmaf(a, w.z, acc.z);
    acc.w = fmaf(a, w.w, acc.w);
}

__device__ __forceinline__ void matvec32(float4 v, const float* __restrict__ w,
                                         int r, float4& acc) {
    const float4* w4 = reinterpret_cast<const float4*>(w);
#pragma unroll
    for (int kk = 0; kk < 8; ++kk) {
        float a0 = __shfl(v.x, kk, 8);
        float a1 = __shfl(v.y, kk, 8);
        float a2 = __shfl(v.z, kk, 8);
        float a3 = __shfl(v.w, kk, 8);
        fma4(acc, a0, w4[(4 * kk + 0) * 8 + r]);
        fma4(acc, a1, w4[(4 * kk + 1) * 8 + r]);
        fma4(acc, a2, w4[(4 * kk + 2) * 8 + r]);
        fma4(acc, a3, w4[(4 * kk + 3) * 8 + r]);
    }
}

__device__ __forceinline__ float4 relu4(float4 v) {
    v.x = fmaxf(v.x, 0.0f); v.y = fmaxf(v.y, 0.0f);
    v.z = fmaxf(v.z, 0.0f); v.w = fmaxf(v.w, 0.0f);
    return v;
}

// ------------------------------- gather helpers -----------------------------
__device__ __forceinline__ void accum8(uint4 w, float dt,
                                       const float* __restrict__ wd,
                                       const float* pp, float* rsum, int base) {
#pragma unroll
    for (int j = 0; j < 4; ++j) {
        unsigned u = (&w.x)[j];
        __half2 hh = *reinterpret_cast<const __half2*>(&u);
        float2 f = __half22float2(hh);
        int c = base + 2 * j;
        rsum[c]     += fmaxf(fmaf(dt, wd[c],     pp[c]     + f.x), 0.0f);
        rsum[c + 1] += fmaxf(fmaf(dt, wd[c + 1], pp[c + 1] + f.y), 0.0f);
    }
}

__device__ __forceinline__ void accum_edge(const __half* __restrict__ q, unsigned rc,
                                           const float* __restrict__ wd,
                                           const float* pp, float* rsum) {
    const uint4* p = reinterpret_cast<const uint4*>(q + (size_t)(rc >> 15) * HID);
    uint4 w0 = p[0], w1 = p[1], w2 = p[2], w3 = p[3];
    float dt = (float)(rc & 32767u) * DIST_INV;
    accum8(w0, dt, wd, pp, rsum, 0);
    accum8(w1, dt, wd, pp, rsum, 8);
    accum8(w2, dt, wd, pp, rsum, 16);
    accum8(w3, dt, wd, pp, rsum, 24);
}

// ------------------------------- model kernels ------------------------------
// encoder fused with layer-0 q projection: writes x (fp32) and q0 (fp16)
__global__ void encoder_kernel(const float* __restrict__ feat,
                               const float* __restrict__ w1, const float* __restrict__ b1,
                               const float* __restrict__ w2, const float* __restrict__ b2,
                               const float* __restrict__ w1b0,  // msg_w1[0] rows 32..63
                               float* __restrict__ xout, __half* __restrict__ qout) {
    int r = threadIdx.x & 7;
    int n = blockIdx.x * NPB4 + (threadIdx.x >> 3);
    const float4* f4 = reinterpret_cast<const float4*>(feat);
    float4 f0 = f4[(size_t)n * 16 + r];
    float4 f1 = f4[(size_t)n * 16 + 8 + r];
    float4 h = reinterpret_cast<const float4*>(b1)[r];
    matvec32(f0, w1, r, h);
    matvec32(f1, w1 + 32 * HID, r, h);
    h = relu4(h);
    float4 y = reinterpret_cast<const float4*>(b2)[r];
    matvec32(h, w2, r, y);
    reinterpret_cast<float4*>(xout)[(size_t)n * 8 + r] = y;
    float4 qq = make_float4(0.f, 0.f, 0.f, 0.f);
    matvec32(y, w1b0, r, qq);
    __half2 ha = __floats2half2_rn(qq.x, qq.y);
    __half2 hb = __floats2half2_rn(qq.z, qq.w);
    uint2 u;
    u.x = *reinterpret_cast<unsigned*>(&ha);
    u.y = *reinterpret_cast<unsigned*>(&hb);
    reinterpret_cast<uint2*>(qout + (size_t)n * HID)[r] = u;
}

// fused per-layer: local p-compute + CSR gather + relu-accum + (@W2 + deg*b2)
// + update MLP + (fp16 q for next layer | output head). Thread-per-node.
// DEPTH-4 edge pipeline, UNCONFOUNDED this time:
//  - x row is NOT kept live through the loop (reloaded after; L2-warm),
//    so loop-live = pp[32]+rsum[32]+batch[64]+misc ~ 145 regs.
//  - __launch_bounds__(256,1) lifts the VGPR cap (r12: compiler clamped to
//    128 and spilled ~2.7MB; occupancy is grid-limited at ~1.5 blocks/CU
//    anyway so extra VGPRs are free).
// Verification: VGPR >= 160 and WRITE_SIZE exactly 18.75MB (no spill).
__global__ __launch_bounds__(256, 1)
void gather_update_kernel(float* __restrict__ x,
                          const __half* __restrict__ q,     // q of this layer (fp16)
                          const unsigned* __restrict__ recs,
                          const int* __restrict__ off,
                          const float* __restrict__ w1,     // msg_w1[l] (65x32)
                          const float* __restrict__ b1,
                          const float* __restrict__ w2,
                          const float* __restrict__ b2,
                          const float* __restrict__ uw1, const float* __restrict__ ub1,
                          const float* __restrict__ uw2, const float* __restrict__ ub2,
                          const float* __restrict__ w1bn,   // msg_w1[l+1] rows 32..63 (or null)
                          __half* __restrict__ qout,        // q for next layer (or null)
                          const float* __restrict__ ow, const float* __restrict__ ob,
                          float* __restrict__ fo) {         // final out (or null)
    int n = blockIdx.x * blockDim.x + threadIdx.x;
    if (n >= N_NODES) return;
    int t0 = off[n];
    int t1 = (n == N_NODES - 1) ? N_EDGES : off[n + 1];

    // p = x_n @ W1[0:32] + b1; the x row is scratch here (reloaded later)
    float pp[HID];
    {
        float xi[HID];
        load_row32(x + (size_t)n * HID, xi);
#pragma unroll
        for (int j = 0; j < HID; ++j) pp[j] = b1[j];
        for (int k = 0; k < HID; ++k) {
            float v = xi[k];
#pragma unroll
            for (int j = 0; j < HID; ++j) pp[j] = fmaf(v, w1[k * HID + j], pp[j]);
        }
    }

    float rsum[HID];
#pragma unroll
    for (int j = 0; j < HID; ++j) rsum[j] = 0.0f;

    const float* __restrict__ wd = w1 + 2 * HID * HID;  // dist row (uniform -> SGPR)

    int t = t0;
    int nrem = t1 - t0;
    if (nrem > 0) {
        int last = t1 - 1;
        unsigned rc0 = recs[t];
        unsigned rc1 = recs[(t + 1 < t1) ? t + 1 : last];
        unsigned rc2 = recs[(t + 2 < t1) ? t + 2 : last];
        unsigned rc3 = recs[(t + 3 < t1) ? t + 3 : last];
        while (nrem >= 4) {
            const uint4* p0 = reinterpret_cast<const uint4*>(q + (size_t)(rc0 >> 15) * HID);
            const uint4* p1 = reinterpret_cast<const uint4*>(q + (size_t)(rc1 >> 15) * HID);
            const uint4* p2 = reinterpret_cast<const uint4*>(q + (size_t)(rc2 >> 15) * HID);
            const uint4* p3 = reinterpret_cast<const uint4*>(q + (size_t)(rc3 >> 15) * HID);
            // issue ALL 16 row loads (4 cache lines in flight per lane)
            uint4 a0 = p0[0], a1 = p0[1], a2 = p0[2], a3 = p0[3];
            uint4 b0 = p1[0], b1_ = p1[1], b2_ = p1[2], b3 = p1[3];
            uint4 c0 = p2[0], c1 = p2[1], c2 = p2[2], c3 = p2[3];
            uint4 d0 = p3[0], d1 = p3[1], d2 = p3[2], d3 = p3[3];
            // prefetch next chunk's recs while rows are in flight
            int tn = t + 4;
            unsigned s0 = recs[(tn     < t1) ? tn     : last];
            unsigned s1 = recs[(tn + 1 < t1) ? tn + 1 : last];
            unsigned s2 = recs[(tn + 2 < t1) ? tn + 2 : last];
            unsigned s3 = recs[(tn + 3 < t1) ? tn + 3 : last];
            // consume (same per-thread accumulation order as depth-1)
            float dt0 = (float)(rc0 & 32767u) * DIST_INV;
            accum8(a0, dt0, wd, pp, rsum, 0);  accum8(a1, dt0, wd, pp, rsum, 8);
            accum8(a2, dt0, wd, pp, rsum, 16); accum8(a3, dt0, wd, pp, rsum, 24);
            float dt1 = (float)(rc1 & 32767u) * DIST_INV;
            accum8(b0, dt1, wd, pp, rsum, 0);  accum8(b1_, dt1, wd, pp, rsum, 8);
            accum8(b2_, dt1, wd, pp, rsum, 16); accum8(b3, dt1, wd, pp, rsum, 24);
            float dt2 = (float)(rc2 & 32767u) * DIST_INV;
            accum8(c0, dt2, wd, pp, rsum, 0);  accum8(c1, dt2, wd, pp, rsum, 8);
            accum8(c2, dt2, wd, pp, rsum, 16); accum8(c3, dt2, wd, pp, rsum, 24);
            float dt3 = (float)(rc3 & 32767u) * DIST_INV;
            accum8(d0, dt3, wd, pp, rsum, 0);  accum8(d1, dt3, wd, pp, rsum, 8);
            accum8(d2, dt3, wd, pp, rsum, 16); accum8(d3, dt3, wd, pp, rsum, 24);
            rc0 = s0; rc1 = s1; rc2 = s2; rc3 = s3;
            t = tn; nrem -= 4;
        }
        if (nrem >= 1) accum_edge(q, rc0, wd, pp, rsum);
        if (nrem >= 2) accum_edge(q, rc1, wd, pp, rsum);
        if (nrem >= 3) accum_edge(q, rc2, wd, pp, rsum);
    }

    // reload x row (L2-warm) and build in = [x, agg]
    float in[2 * HID];
    load_row32(x + (size_t)n * HID, in);
    float deg = (float)(t1 - t0);
#pragma unroll
    for (int j = 0; j < HID; ++j) in[HID + j] = b2[j] * deg;
    for (int k = 0; k < HID; ++k) {
        float v = rsum[k];
#pragma unroll
        for (int j = 0; j < HID; ++j) in[HID + j] = fmaf(v, w2[k * HID + j], in[HID + j]);
    }
    float y[HID];
    mlp2<2 * HID>(in, uw1, ub1, uw2, ub2, y);

    if (fo != nullptr) {
        // final layer: output head only
        float z[HID];
#pragma unroll
        for (int j = 0; j < HID; ++j) z[j] = ob[j];
        for (int k = 0; k < HID; ++k) {
            float v = y[k];
#pragma unroll
            for (int j = 0; j < HID; ++j) z[j] = fmaf(v, ow[k * HID + j], z[j]);
        }
        store_row32(fo + (size_t)n * HID, z);
    } else {
        store_row32(x + (size_t)n * HID, y);
        // q for next layer: y @ W1b(l+1), stored fp16
        float qn[HID];
#pragma unroll
        for (int j = 0; j < HID; ++j) qn[j] = 0.0f;
        for (int k = 0; k < HID; ++k) {
            float v = y[k];
#pragma unroll
            for (int j = 0; j < HID; ++j) qn[j] = fmaf(v, w1bn[k * HID + j], qn[j]);
        }
        store_qrow_h(qout + (size_t)n * HID, qn);
    }
}

// ---------------------------------------------------------------------------
extern "C" void kernel_launch(void* const* d_in, const int* in_sizes, int n_in,
                              void* d_out, int out_size, void* d_ws, size_t ws_size,
                              hipStream_t stream) {
    const float* node_feat = (const float*)d_in[0];
    const float* pos       = (const float*)d_in[1];
    const int*   ei        = (const int*)  d_in[2];   // int32 on device
    const float* enc_w1    = (const float*)d_in[3];
    const float* enc_b1    = (const float*)d_in[4];
    const float* enc_w2    = (const float*)d_in[5];
    const float* enc_b2    = (const float*)d_in[6];
    const float* msg_w1    = (const float*)d_in[7];   // [3, 65, 32]
    const float* msg_b1    = (const float*)d_in[8];
    const float* msg_w2    = (const float*)d_in[9];   // [3, 32, 32]
    const float* msg_b2    = (const float*)d_in[10];
    const float* upd_w1    = (const float*)d_in[11];  // [3, 64, 32]
    const float* upd_b1    = (const float*)d_in[12];
    const float* upd_w2    = (const float*)d_in[13];
    const float* upd_b2    = (const float*)d_in[14];
    const float* out_w     = (const float*)d_in[15];
    const float* out_b     = (const float*)d_in[16];
    float* out = (float*)d_out;

    // workspace layout, ~33 MB total
    char* ws = (char*)d_ws;
    float*    x    = (float*)ws;                                  // N*32 f32
    __half*   qA   = (__half*)(x + (size_t)N_NODES * HID);        // N*32 f16
    __half*   qB   = qA + (size_t)N_NODES * HID;                  // N*32 f16
    unsigned* recs = (unsigned*)(qB + (size_t)N_NODES * HID);     // E u32
    int*      posm = (int*)(recs + (size_t)N_EDGES);              // N
    int*      cnt  = posm + N_NODES;                              // N
    int*      off  = cnt + N_NODES;                               // N+1
    int*      bsum = off + (N_NODES + 1);                         // <=256
    int*      boff = bsum + 256;                                  // <=256

    const int B = 256;
    const int gridE4 = (N_EDGES / 4 + B - 1) / B;
    const int gridE8 = (N_EDGES / 8 + B - 1) / B;
    const int gridN  = (N_NODES + B - 1) / B;
    const int NB = (N_NODES + SCAN_B - 1) / SCAN_B;               // 98

    // ---- build CSR (once per launch) ----
    zero_int_kernel<<<gridN, B, 0, stream>>>(cnt, N_NODES);
    count_kernel<<<gridE4, B, 0, stream>>>(ei, cnt);
    scan1_kernel<<<NB, 256, 0, stream>>>(cnt, off, bsum);
    scan2_kernel<<<1, 256, 0, stream>>>(bsum, boff, NB);
    scan3_kernel<<<gridN, B, 0, stream>>>(off, posm, boff);
    scatter_kernel<<<gridE8, B, 0, stream>>>(ei, pos, posm, recs);

    // ---- model ----
    encoder_kernel<<<GRID4, B, 0, stream>>>(node_feat, enc_w1, enc_b1, enc_w2, enc_b2,
                                            msg_w1 + (size_t)HID * HID,  // layer-0 W1 rows 32..63
                                            x, qA);

    __half* qbuf[2] = {qA, qB};
    for (int l = 0; l < NUM_LAYERS; ++l) {
        const float* w1 = msg_w1 + (size_t)l * (2 * HID + 1) * HID;
        bool last = (l == NUM_LAYERS - 1);
        const float* w1bn = last ? nullptr
            : msg_w1 + (size_t)(l + 1) * (2 * HID + 1) * HID + (size_t)HID * HID;
        gather_update_kernel<<<gridN, B, 0, stream>>>(
            x, qbuf[l & 1], recs, off,
            w1,
            msg_b1 + (size_t)l * HID,
            msg_w2 + (size_t)l * HID * HID,
            msg_b2 + (size_t)l * HID,
            upd_w1 + (size_t)l * (2 * HID) * HID,
            upd_b1 + (size_t)l * HID,
            upd_w2 + (size_t)l * HID * HID,
            upd_b2 + (size_t)l * HID,
            w1bn,
            last ? nullptr : qbuf[(l + 1) & 1],
            last ? out_w : nullptr,
            last ? out_b : nullptr,
            last ? out : nullptr);
    }
}

// Round 14
// 464.117 us; speedup vs baseline: 1.4511x; 1.4511x over previous
//
#include <hip/hip_runtime.h>
#include <hip/hip_fp16.h>

#define N_NODES  100000
#define N_EDGES  1600000
#define NODE_DIM 64
#define HID      32
#define NUM_LAYERS 3
#define SCAN_B   1024   // elements per scan1 block

// 8-lane encoder decomposition
#define NPB4  32
#define GRID4 (N_NODES / NPB4)   // 3125, exact

// dist quantization: 15-bit fixed point, scale 2048 (dist < 16 w.p. ~1)
#define DIST_SCALE 2048.0f
#define DIST_INV   (1.0f / 2048.0f)

// ---------------------------------------------------------------------------
template <int IN>
__device__ __forceinline__ void mlp2(const float (&in)[IN],
                                     const float* __restrict__ w1,
                                     const float* __restrict__ b1,
                                     const float* __restrict__ w2,
                                     const float* __restrict__ b2,
                                     float (&out)[HID]) {
    float h[HID];
#pragma unroll
    for (int j = 0; j < HID; ++j) h[j] = b1[j];
    for (int k = 0; k < IN; ++k) {
        float v = in[k];
#pragma unroll
        for (int j = 0; j < HID; ++j) h[j] = fmaf(v, w1[k * HID + j], h[j]);
    }
#pragma unroll
    for (int j = 0; j < HID; ++j) h[j] = fmaxf(h[j], 0.0f);
#pragma unroll
    for (int j = 0; j < HID; ++j) out[j] = b2[j];
    for (int k = 0; k < HID; ++k) {
        float v = h[k];
#pragma unroll
        for (int j = 0; j < HID; ++j) out[j] = fmaf(v, w2[k * HID + j], out[j]);
    }
}

__device__ __forceinline__ void load_row32(const float* __restrict__ p, float* dst) {
    const float4* p4 = reinterpret_cast<const float4*>(p);
#pragma unroll
    for (int k = 0; k < HID / 4; ++k) {
        float4 v = p4[k];
        dst[4 * k + 0] = v.x; dst[4 * k + 1] = v.y;
        dst[4 * k + 2] = v.z; dst[4 * k + 3] = v.w;
    }
}

__device__ __forceinline__ void store_row32(float* __restrict__ p, const float* src) {
    float4* p4 = reinterpret_cast<float4*>(p);
#pragma unroll
    for (int k = 0; k < HID / 4; ++k) {
        float4 v;
        v.x = src[4 * k + 0]; v.y = src[4 * k + 1];
        v.z = src[4 * k + 2]; v.w = src[4 * k + 3];
        p4[k] = v;
    }
}

__device__ __forceinline__ void store_qrow_h(__half* __restrict__ qrow, const float* y) {
    uint4* p = reinterpret_cast<uint4*>(qrow);
#pragma unroll
    for (int i = 0; i < 4; ++i) {
        uint4 w;
#pragma unroll
        for (int j = 0; j < 4; ++j) {
            __half2 hh = __floats2half2_rn(y[i * 8 + j * 2], y[i * 8 + j * 2 + 1]);
            (&w.x)[j] = *reinterpret_cast<unsigned*>(&hh);
        }
        p[i] = w;
    }
}

// ------------------------------- sort: CSR by dst ---------------------------
__global__ void zero_int_kernel(int* __restrict__ p, int n) {
    int i = blockIdx.x * blockDim.x + threadIdx.x;
    if (i < n) p[i] = 0;
}

__global__ void rank_kernel(const int* __restrict__ ei,
                            int* __restrict__ cnt, int* __restrict__ rank) {
    int e = blockIdx.x * blockDim.x + threadIdx.x;
    if (e >= N_EDGES) return;
    int d = ei[N_EDGES + e];
    rank[e] = atomicAdd(&cnt[d], 1);
}

// scan1: per-block exclusive scan of cnt (1024 elems/block of 256 threads)
__global__ void scan1_kernel(const int* __restrict__ cnt, int* __restrict__ off,
                             int* __restrict__ bsum) {
    __shared__ int lds[256];
    int tid = threadIdx.x;
    int base = blockIdx.x * SCAN_B + tid * 4;
    int v0 = (base + 0 < N_NODES) ? cnt[base + 0] : 0;
    int v1 = (base + 1 < N_NODES) ? cnt[base + 1] : 0;
    int v2 = (base + 2 < N_NODES) ? cnt[base + 2] : 0;
    int v3 = (base + 3 < N_NODES) ? cnt[base + 3] : 0;
    int s1 = v0, s2 = v0 + v1, s3 = v0 + v1 + v2;
    int tsum = s3 + v3;
    lds[tid] = tsum;
    __syncthreads();
    for (int d = 1; d < 256; d <<= 1) {
        int t = lds[tid];
        int u = (tid >= d) ? lds[tid - d] : 0;
        __syncthreads();
        lds[tid] = t + u;
        __syncthreads();
    }
    int excl = lds[tid] - tsum;
    if (base + 0 < N_NODES) off[base + 0] = excl;
    if (base + 1 < N_NODES) off[base + 1] = excl + s1;
    if (base + 2 < N_NODES) off[base + 2] = excl + s2;
    if (base + 3 < N_NODES) off[base + 3] = excl + s3;
    if (tid == 255) bsum[blockIdx.x] = lds[255];
}

__global__ void scan2_kernel(const int* __restrict__ bsum, int* __restrict__ boff, int nb) {
    __shared__ int lds[256];
    int tid = threadIdx.x;
    int v = (tid < nb) ? bsum[tid] : 0;
    lds[tid] = v;
    __syncthreads();
    for (int d = 1; d < 256; d <<= 1) {
        int t = lds[tid];
        int u = (tid >= d) ? lds[tid - d] : 0;
        __syncthreads();
        lds[tid] = t + u;
        __syncthreads();
    }
    if (tid < nb) boff[tid] = lds[tid] - v;
}

__global__ void scan3_kernel(int* __restrict__ off, const int* __restrict__ boff) {
    int i = blockIdx.x * blockDim.x + threadIdx.x;
    if (i < N_NODES) off[i] += boff[i / SCAN_B];
}

// scatter: 4 edges per thread, ONE packed 4B store per edge:
// rec = (s << 15) | round(dist * 2048)  (s < 2^17, dist < 16, err 2.4e-4).
__global__ void scatter_kernel(const int* __restrict__ ei,
                               const float* __restrict__ pos,
                               const int* __restrict__ off,
                               const int* __restrict__ rank,
                               unsigned* __restrict__ recs) {
    int e0 = (blockIdx.x * blockDim.x + threadIdx.x) * 4;
    if (e0 >= N_EDGES) return;   // N_EDGES % 4 == 0, so all 4 are valid
    int4 ss = *reinterpret_cast<const int4*>(ei + e0);
    int4 dd = *reinterpret_cast<const int4*>(ei + N_EDGES + e0);
    int4 rk = *reinterpret_cast<const int4*>(rank + e0);
    int sA[4] = {ss.x, ss.y, ss.z, ss.w};
    int dA[4] = {dd.x, dd.y, dd.z, dd.w};
    int rA[4] = {rk.x, rk.y, rk.z, rk.w};
#pragma unroll
    for (int k = 0; k < 4; ++k) {
        int s = sA[k], d = dA[k];
        float dx = pos[d * 3 + 0] - pos[s * 3 + 0];
        float dy = pos[d * 3 + 1] - pos[s * 3 + 1];
        float dz = pos[d * 3 + 2] - pos[s * 3 + 2];
        float dist = sqrtf(dx * dx + dy * dy + dz * dz);
        int dq = (int)(dist * DIST_SCALE);
        if (dq > 32767) dq = 32767;
        int t = off[d] + rA[k];
        recs[t] = ((unsigned)s << 15) | (unsigned)dq;
    }
}

// ------------------------------- model helpers (8-lane) ---------------------
__device__ __forceinline__ void fma4(float4& acc, float a, const float4 w) {
    acc.x = fmaf(a, w.x, acc.x);
    acc.y = fmaf(a, w.y, acc.y);
    acc.z = fmaf(a, w.z, acc.z);
    acc.w = fmaf(a, w.w, acc.w);
}

__device__ __forceinline__ void matvec32(float4 v, const float* __restrict__ w,
                                         int r, float4& acc) {
    const float4* w4 = reinterpret_cast<const float4*>(w);
#pragma unroll
    for (int kk = 0; kk < 8; ++kk) {
        float a0 = __shfl(v.x, kk, 8);
        float a1 = __shfl(v.y, kk, 8);
        float a2 = __shfl(v.z, kk, 8);
        float a3 = __shfl(v.w, kk, 8);
        fma4(acc, a0, w4[(4 * kk + 0) * 8 + r]);
        fma4(acc, a1, w4[(4 * kk + 1) * 8 + r]);
        fma4(acc, a2, w4[(4 * kk + 2) * 8 + r]);
        fma4(acc, a3, w4[(4 * kk + 3) * 8 + r]);
    }
}

__device__ __forceinline__ float4 relu4(float4 v) {
    v.x = fmaxf(v.x, 0.0f); v.y = fmaxf(v.y, 0.0f);
    v.z = fmaxf(v.z, 0.0f); v.w = fmaxf(v.w, 0.0f);
    return v;
}

// ------------------------------- gather helpers -----------------------------
__device__ __forceinline__ void accum8(uint4 w, float dt,
                                       const float* __restrict__ wd,
                                       const float* pp, float* rsum, int base) {
#pragma unroll
    for (int j = 0; j < 4; ++j) {
        unsigned u = (&w.x)[j];
        __half2 hh = *reinterpret_cast<const __half2*>(&u);
        float2 f = __half22float2(hh);
        int c = base + 2 * j;
        rsum[c]     += fmaxf(fmaf(dt, wd[c],     pp[c]     + f.x), 0.0f);
        rsum[c + 1] += fmaxf(fmaf(dt, wd[c + 1], pp[c + 1] + f.y), 0.0f);
    }
}

__device__ __forceinline__ void accum_edge(const __half* __restrict__ q, unsigned rc,
                                           const float* __restrict__ wd,
                                           const float* pp, float* rsum) {
    const uint4* p = reinterpret_cast<const uint4*>(q + (size_t)(rc >> 15) * HID);
    uint4 w0 = p[0], w1 = p[1], w2 = p[2], w3 = p[3];
    float dt = (float)(rc & 32767u) * DIST_INV;
    accum8(w0, dt, wd, pp, rsum, 0);
    accum8(w1, dt, wd, pp, rsum, 8);
    accum8(w2, dt, wd, pp, rsum, 16);
    accum8(w3, dt, wd, pp, rsum, 24);
}

// ------------------------------- model kernels ------------------------------
// encoder fused with layer-0 q projection: writes x (fp32) and q0 (fp16)
__global__ void encoder_kernel(const float* __restrict__ feat,
                               const float* __restrict__ w1, const float* __restrict__ b1,
                               const float* __restrict__ w2, const float* __restrict__ b2,
                               const float* __restrict__ w1b0,  // msg_w1[0] rows 32..63
                               float* __restrict__ xout, __half* __restrict__ qout) {
    int r = threadIdx.x & 7;
    int n = blockIdx.x * NPB4 + (threadIdx.x >> 3);
    const float4* f4 = reinterpret_cast<const float4*>(feat);
    float4 f0 = f4[(size_t)n * 16 + r];
    float4 f1 = f4[(size_t)n * 16 + 8 + r];
    float4 h = reinterpret_cast<const float4*>(b1)[r];
    matvec32(f0, w1, r, h);
    matvec32(f1, w1 + 32 * HID, r, h);
    h = relu4(h);
    float4 y = reinterpret_cast<const float4*>(b2)[r];
    matvec32(h, w2, r, y);
    reinterpret_cast<float4*>(xout)[(size_t)n * 8 + r] = y;
    float4 qq = make_float4(0.f, 0.f, 0.f, 0.f);
    matvec32(y, w1b0, r, qq);
    __half2 ha = __floats2half2_rn(qq.x, qq.y);
    __half2 hb = __floats2half2_rn(qq.z, qq.w);
    uint2 u;
    u.x = *reinterpret_cast<unsigned*>(&ha);
    u.y = *reinterpret_cast<unsigned*>(&hb);
    reinterpret_cast<uint2*>(qout + (size_t)n * HID)[r] = u;
}

// fused per-layer: local p-compute + CSR gather (fp16 q rows, DEPTH-2 pipeline)
// + relu-accum + (@W2 + deg*b2) + update MLP + (fp16 q for next layer | head).
// Thread-per-node. Depth-2: 2 rows (8 uint4 = 32 regs) in flight + rec
// prefetch; x row reloaded AFTER the loop (L2-warm) to keep loop-live ~115.
// __launch_bounds__(256,2): VGPR cap 128 — MUST stay <=128 (r13: 132 VGPR
// crossed the occupancy cliff, 16%->8.7%, 1.7x slower). Spill detector:
// WRITE_SIZE must be exactly 18.75MB.
__global__ __launch_bounds__(256, 2)
void gather_update_kernel(float* __restrict__ x,
                          const __half* __restrict__ q,     // q of this layer (fp16)
                          const unsigned* __restrict__ recs,
                          const int* __restrict__ off,
                          const float* __restrict__ w1,     // msg_w1[l] (65x32)
                          const float* __restrict__ b1,
                          const float* __restrict__ w2,
                          const float* __restrict__ b2,
                          const float* __restrict__ uw1, const float* __restrict__ ub1,
                          const float* __restrict__ uw2, const float* __restrict__ ub2,
                          const float* __restrict__ w1bn,   // msg_w1[l+1] rows 32..63 (or null)
                          __half* __restrict__ qout,        // q for next layer (or null)
                          const float* __restrict__ ow, const float* __restrict__ ob,
                          float* __restrict__ fo) {         // final out (or null)
    int n = blockIdx.x * blockDim.x + threadIdx.x;
    if (n >= N_NODES) return;
    int t0 = off[n];
    int t1 = (n == N_NODES - 1) ? N_EDGES : off[n + 1];

    // p = x_n @ W1[0:32] + b1; the x row is scratch here (reloaded later)
    float pp[HID];
    {
        float xi[HID];
        load_row32(x + (size_t)n * HID, xi);
#pragma unroll
        for (int j = 0; j < HID; ++j) pp[j] = b1[j];
        for (int k = 0; k < HID; ++k) {
            float v = xi[k];
#pragma unroll
            for (int j = 0; j < HID; ++j) pp[j] = fmaf(v, w1[k * HID + j], pp[j]);
        }
    }

    float rsum[HID];
#pragma unroll
    for (int j = 0; j < HID; ++j) rsum[j] = 0.0f;

    const float* __restrict__ wd = w1 + 2 * HID * HID;  // dist row (uniform -> SGPR)

    int t = t0;
    int nrem = t1 - t0;
    if (nrem > 0) {
        int last = t1 - 1;
        // preload 2 recs (clamped dupes are valid (s,dist) pairs; tail-guarded)
        unsigned rc0 = recs[t];
        unsigned rc1 = recs[(t + 1 < t1) ? t + 1 : last];
        while (nrem >= 2) {
            const uint4* p0 = reinterpret_cast<const uint4*>(q + (size_t)(rc0 >> 15) * HID);
            const uint4* p1 = reinterpret_cast<const uint4*>(q + (size_t)(rc1 >> 15) * HID);
            // issue both rows' loads (2 cache lines in flight per lane)
            uint4 a0 = p0[0], a1 = p0[1], a2 = p0[2], a3 = p0[3];
            uint4 b0 = p1[0], b1_ = p1[1], b2_ = p1[2], b3 = p1[3];
            // prefetch next pair's recs while rows are in flight
            int tn = t + 2;
            unsigned s0 = recs[(tn     < t1) ? tn     : last];
            unsigned s1 = recs[(tn + 1 < t1) ? tn + 1 : last];
            // consume (same per-thread accumulation order as depth-1)
            float dt0 = (float)(rc0 & 32767u) * DIST_INV;
            accum8(a0, dt0, wd, pp, rsum, 0);  accum8(a1, dt0, wd, pp, rsum, 8);
            accum8(a2, dt0, wd, pp, rsum, 16); accum8(a3, dt0, wd, pp, rsum, 24);
            float dt1 = (float)(rc1 & 32767u) * DIST_INV;
            accum8(b0, dt1, wd, pp, rsum, 0);  accum8(b1_, dt1, wd, pp, rsum, 8);
            accum8(b2_, dt1, wd, pp, rsum, 16); accum8(b3, dt1, wd, pp, rsum, 24);
            rc0 = s0; rc1 = s1;
            t = tn; nrem -= 2;
        }
        if (nrem == 1) accum_edge(q, rc0, wd, pp, rsum);
    }

    // reload x row (L2-warm) and build in = [x, agg]
    float in[2 * HID];
    load_row32(x + (size_t)n * HID, in);
    float deg = (float)(t1 - t0);
#pragma unroll
    for (int j = 0; j < HID; ++j) in[HID + j] = b2[j] * deg;
    for (int k = 0; k < HID; ++k) {
        float v = rsum[k];
#pragma unroll
        for (int j = 0; j < HID; ++j) in[HID + j] = fmaf(v, w2[k * HID + j], in[HID + j]);
    }
    float y[HID];
    mlp2<2 * HID>(in, uw1, ub1, uw2, ub2, y);

    if (fo != nullptr) {
        // final layer: output head only
        float z[HID];
#pragma unroll
        for (int j = 0; j < HID; ++j) z[j] = ob[j];
        for (int k = 0; k < HID; ++k) {
            float v = y[k];
#pragma unroll
            for (int j = 0; j < HID; ++j) z[j] = fmaf(v, ow[k * HID + j], z[j]);
        }
        store_row32(fo + (size_t)n * HID, z);
    } else {
        store_row32(x + (size_t)n * HID, y);
        // q for next layer: y @ W1b(l+1), stored fp16
        float qn[HID];
#pragma unroll
        for (int j = 0; j < HID; ++j) qn[j] = 0.0f;
        for (int k = 0; k < HID; ++k) {
            float v = y[k];
#pragma unroll
            for (int j = 0; j < HID; ++j) qn[j] = fmaf(v, w1bn[k * HID + j], qn[j]);
        }
        store_qrow_h(qout + (size_t)n * HID, qn);
    }
}

// ---------------------------------------------------------------------------
extern "C" void kernel_launch(void* const* d_in, const int* in_sizes, int n_in,
                              void* d_out, int out_size, void* d_ws, size_t ws_size,
                              hipStream_t stream) {
    const float* node_feat = (const float*)d_in[0];
    const float* pos       = (const float*)d_in[1];
    const int*   ei        = (const int*)  d_in[2];   // int32 on device
    const float* enc_w1    = (const float*)d_in[3];
    const float* enc_b1    = (const float*)d_in[4];
    const float* enc_w2    = (const float*)d_in[5];
    const float* enc_b2    = (const float*)d_in[6];
    const float* msg_w1    = (const float*)d_in[7];   // [3, 65, 32]
    const float* msg_b1    = (const float*)d_in[8];
    const float* msg_w2    = (const float*)d_in[9];   // [3, 32, 32]
    const float* msg_b2    = (const float*)d_in[10];
    const float* upd_w1    = (const float*)d_in[11];  // [3, 64, 32]
    const float* upd_b1    = (const float*)d_in[12];
    const float* upd_w2    = (const float*)d_in[13];
    const float* upd_b2    = (const float*)d_in[14];
    const float* out_w     = (const float*)d_in[15];
    const float* out_b     = (const float*)d_in[16];
    float* out = (float*)d_out;

    // workspace layout, ~39 MB total
    char* ws = (char*)d_ws;
    float*    x    = (float*)ws;                                  // N*32 f32
    __half*   qA   = (__half*)(x + (size_t)N_NODES * HID);        // N*32 f16
    __half*   qB   = qA + (size_t)N_NODES * HID;                  // N*32 f16
    unsigned* recs = (unsigned*)(qB + (size_t)N_NODES * HID);     // E u32
    int*      rank = (int*)(recs + (size_t)N_EDGES);              // E
    int*      cnt  = rank + (size_t)N_EDGES;                      // N
    int*      off  = cnt + N_NODES;                               // N+1
    int*      bsum = off + (N_NODES + 1);                         // <=256
    int*      boff = bsum + 256;                                  // <=256

    const int B = 256;
    const int gridE  = (N_EDGES + B - 1) / B;
    const int gridE4 = (N_EDGES / 4 + B - 1) / B;
    const int gridN  = (N_NODES + B - 1) / B;
    const int NB = (N_NODES + SCAN_B - 1) / SCAN_B;               // 98

    // ---- build CSR (once per launch) ----
    zero_int_kernel<<<gridN, B, 0, stream>>>(cnt, N_NODES);
    rank_kernel<<<gridE, B, 0, stream>>>(ei, cnt, rank);
    scan1_kernel<<<NB, 256, 0, stream>>>(cnt, off, bsum);
    scan2_kernel<<<1, 256, 0, stream>>>(bsum, boff, NB);
    scan3_kernel<<<gridN, B, 0, stream>>>(off, boff);
    scatter_kernel<<<gridE4, B, 0, stream>>>(ei, pos, off, rank, recs);

    // ---- model ----
    encoder_kernel<<<GRID4, B, 0, stream>>>(node_feat, enc_w1, enc_b1, enc_w2, enc_b2,
                                            msg_w1 + (size_t)HID * HID,  // layer-0 W1 rows 32..63
                                            x, qA);

    __half* qbuf[2] = {qA, qB};
    for (int l = 0; l < NUM_LAYERS; ++l) {
        const float* w1 = msg_w1 + (size_t)l * (2 * HID + 1) * HID;
        bool last = (l == NUM_LAYERS - 1);
        const float* w1bn = last ? nullptr
            : msg_w1 + (size_t)(l + 1) * (2 * HID + 1) * HID + (size_t)HID * HID;
        gather_update_kernel<<<gridN, B, 0, stream>>>(
            x, qbuf[l & 1], recs, off,
            w1,
            msg_b1 + (size_t)l * HID,
            msg_w2 + (size_t)l * HID * HID,
            msg_b2 + (size_t)l * HID,
            upd_w1 + (size_t)l * (2 * HID) * HID,
            upd_b1 + (size_t)l * HID,
            upd_w2 + (size_t)l * HID * HID,
            upd_b2 + (size_t)l * HID,
            w1bn,
            last ? nullptr : qbuf[(l + 1) & 1],
            last ? out_w : nullptr,
            last ? out_b : nullptr,
            last ? out : nullptr);
    }
}